// Round 11
// baseline (472.688 us; speedup 1.0000x reference)
//
#include <hip/hip_runtime.h>
#include <hip/hip_bf16.h>

// Problem sizes (fixed)
#define B_SZ 131072
#define F_SZ 784
#define H_SZ 392
#define D_SZ 28
#define K_SZ 512
#define BM   64
#define NBLK (B_SZ / BM)   // 2048

typedef __attribute__((ext_vector_type(8))) short short8v;
typedef __attribute__((ext_vector_type(4))) short short4v;
typedef __attribute__((ext_vector_type(4))) float f32x4;

__device__ inline short f2bf(float f) {
  __hip_bfloat16 h = __float2bfloat16(f);
  return __builtin_bit_cast(short, h);
}

__device__ inline void glds16(const short* src, short* dst) {
  __builtin_amdgcn_global_load_lds(
      (const __attribute__((address_space(1))) unsigned int*)src,
      (__attribute__((address_space(3))) unsigned int*)dst, 16, 0, 0);
}

// ws layout (float offsets)
#define WS_PN2   401408
#define WS_P1    532992
#define WS_PR    535040
#define WS_W1T   537088     // 448x800 bf16 (+64 padded rows read harmlessly)
#define WS_W2T   716288
#define WS_M2P   722944

// ---------------------------------------------------------------------------
// Decoder table: x_rec_table[k] = relu(prior[k]@W3+b3)@W4 + b4 ; pn2[k]
// ---------------------------------------------------------------------------
__global__ __launch_bounds__(256) void precompute_kernel(
    const float* __restrict__ W3, const float* __restrict__ b3,
    const float* __restrict__ W4, const float* __restrict__ b4,
    const float* __restrict__ prior,
    float* __restrict__ table, float* __restrict__ pn2) {
  __shared__ float ps[D_SZ];
  __shared__ float h2s[H_SZ];
  const int k = blockIdx.x;
  const int t = threadIdx.x;
  if (t < D_SZ) ps[t] = prior[k * D_SZ + t];
  __syncthreads();
  for (int j = t; j < H_SZ; j += 256) {
    float acc = b3[j];
    #pragma unroll
    for (int d = 0; d < D_SZ; ++d) acc += ps[d] * W3[d * H_SZ + j];
    h2s[j] = fmaxf(acc, 0.f);
  }
  if (t == 0) {
    float s = 0.f;
    #pragma unroll
    for (int d = 0; d < D_SZ; ++d) s += ps[d] * ps[d];
    pn2[k] = s;
  }
  __syncthreads();
  for (int f = t; f < F_SZ; f += 256) {
    float acc = b4[f];
    for (int j = 0; j < H_SZ; ++j) acc += h2s[j] * W4[j * F_SZ + f];
    table[(size_t)k * F_SZ + f] = acc;
  }
}

// ---------------------------------------------------------------------------
// W1T[c][k] = bf16(W1[k][c]), [448][800], zero-padded. LDS-tiled transpose.
// ---------------------------------------------------------------------------
__global__ __launch_bounds__(256) void w1t_kernel(const float* __restrict__ W1,
                                                  short* __restrict__ W1T) {
  __shared__ float tile[64][65];
  const int k0 = blockIdx.x * 64;
  const int c0 = blockIdx.y * 64;
  const int t = threadIdx.x;
  for (int i = t; i < 4096; i += 256) {
    const int kk = i >> 6, cc = i & 63;
    const int k = k0 + kk, c = c0 + cc;
    tile[kk][cc] = (k < F_SZ && c < H_SZ) ? W1[(size_t)k * H_SZ + c] : 0.f;
  }
  __syncthreads();
  for (int i = t; i < 4096; i += 256) {
    const int cc = i >> 6, kk = i & 63;
    const int k = k0 + kk, c = c0 + cc;
    if (k < 800) W1T[(size_t)c * 800 + k] = f2bf(tile[kk][cc]);
  }
}

// ---------------------------------------------------------------------------
// W2T[d][j] = bf16(W2[j][d]) [32][416] ; M2P[c][d] = bf16(-2*prior[c][d]) [512][32]
// ---------------------------------------------------------------------------
__global__ __launch_bounds__(256) void prep2_kernel(
    const float* __restrict__ W2, const float* __restrict__ prior,
    short* __restrict__ W2T, short* __restrict__ M2P) {
  const int i = blockIdx.x * 256 + threadIdx.x;
  if (i < 32 * 416) {
    const int d = i / 416, j = i % 416;
    W2T[i] = f2bf((d < D_SZ && j < H_SZ) ? W2[(size_t)j * D_SZ + d] : 0.f);
  }
  if (i < K_SZ * 32) {
    const int c = i / 32, dd = i % 32;
    M2P[i] = f2bf((dd < D_SZ) ? -2.f * prior[(size_t)c * D_SZ + dd] : 0.f);
  }
}

// ---------------------------------------------------------------------------
// Fused encoder v11: TRIPLE-buffered Ws/Xs -> glds issued at step k land by
// step k+1's write-point wait (vmcnt(5)), consumed at step k+2.  The
// end-of-step barrier has NO vmcnt: the 5 newest loads (for k+2) stay in
// flight across it.  All buffer indices and VMEM counts are compile-time.
// Geometry r9-exact: BM=64, BK=32, 512 thr / 8 waves (2M x 4N), acc[2][7].
// LDS 113KB -> 1 block/CU.  Tails fused, r9-exact math.
// ---------------------------------------------------------------------------
union WHS { short Ws[3][512 * 32]; short hs[64 * 448]; };   // 98,304 B
union XZS { short Xs[3][64][32];   short zs[64][32];  };    // 12,288 B

// K step: RB = K%3 (read), WB = (K+1)%3 (X write), GB = (K+2)%3 (glds dst)
#define GSTEP(K, RB, WB, GB, ISSUE, DOWRITE) do {                             \
    float4 xq = {0.f, 0.f, 0.f, 0.f};                                         \
    if (ISSUE) {                                                              \
      const int k2_ = ((K) + 2) * 32;                                         \
      _Pragma("unroll")                                                       \
      for (int i_ = 0; i_ < 4; ++i_) {                                        \
        const int ci_ = w + 8 * i_;                                           \
        const int c_ = ci_ * 16 + wrow_sub;                                   \
        const int srcg_ = wgr ^ ((c_ >> 1) & 3);                              \
        glds16(W1T + (size_t)c_ * 800 + k2_ + srcg_ * 8,                      \
               &wh.Ws[GB][ci_ * 512]);                                        \
      }                                                                       \
      __builtin_amdgcn_sched_barrier(0);                                      \
      const int kg_ = k2_ + hg * 4;                                           \
      if (kg_ < F_SZ) xq = *(const float4*)(xrow + kg_);                      \
      __builtin_amdgcn_sched_barrier(0);                                      \
    }                                                                         \
    short8v afr_[2];                                                          \
    _Pragma("unroll")                                                         \
    for (int mt_ = 0; mt_ < 2; ++mt_) {                                       \
      const int row_ = wm * 32 + mt_ * 16 + lr;                               \
      const int pg_ = lg ^ ((row_ >> 1) & 3);                                 \
      afr_[mt_] = *(const short8v*)&xz.Xs[RB][row_][pg_ * 8];                 \
    }                                                                         \
    _Pragma("unroll")                                                         \
    for (int nt_ = 0; nt_ < 7; ++nt_) {                                       \
      const int c_ = wn * 112 + nt_ * 16 + lr;                                \
      const int pgb_ = lg ^ ((c_ >> 1) & 3);                                  \
      const short8v bfr_ = *(const short8v*)&wh.Ws[RB][c_ * 32 + pgb_ * 8];   \
      _Pragma("unroll")                                                       \
      for (int mt_ = 0; mt_ < 2; ++mt_)                                       \
        acc[mt_][nt_] = __builtin_amdgcn_mfma_f32_16x16x32_bf16(              \
            afr_[mt_], bfr_, acc[mt_][nt_], 0, 0, 0);                         \
    }                                                                         \
    if (DOWRITE) {                                                            \
      if (ISSUE) asm volatile("s_waitcnt vmcnt(5)" ::: "memory");             \
      else       asm volatile("s_waitcnt vmcnt(0)" ::: "memory");             \
      short4v p_;                                                             \
      p_[0] = f2bf(xp.x); p_[1] = f2bf(xp.y);                                 \
      p_[2] = f2bf(xp.z); p_[3] = f2bf(xp.w);                                 \
      *(short4v*)&xz.Xs[WB][sr][xslot] = p_;                                  \
      xp = xq;                                                                \
    }                                                                         \
    asm volatile("s_waitcnt lgkmcnt(0)" ::: "memory");                        \
    __builtin_amdgcn_s_barrier();                                             \
  } while (0)

__global__ __launch_bounds__(512, 2) void encoder_kernel(
    const float* __restrict__ X, const short* __restrict__ W1T,
    const float* __restrict__ b1, const short* __restrict__ W2T,
    const float* __restrict__ b2, const short* __restrict__ M2P,
    const float* __restrict__ pn2, const float* __restrict__ table,
    float* __restrict__ partial1, float* __restrict__ partialR) {
  __shared__ WHS wh;                // 98,304 B
  __shared__ XZS xz;                // 12,288 B
  __shared__ float pn2s[K_SZ];      //  2,048 B
  __shared__ float zn2p[2][BM];     //    512 B
  __shared__ int   idxs[BM];        //    256 B
  __shared__ float red1[8], redR[8];

  const int t = threadIdx.x;
  const int w = t >> 6;        // wave 0..7
  const int l = t & 63;
  const int lr = l & 15;
  const int lg = l >> 4;       // 0..3
  const int wm = w >> 2;       // M-half: rows wm*32..
  const int wn = w & 3;        // N-quarter: cols wn*112..
  const int row0 = blockIdx.x * BM;

  f32x4 acc[2][7];
  #pragma unroll
  for (int mt = 0; mt < 2; ++mt)
    #pragma unroll
    for (int nt = 0; nt < 7; ++nt) acc[mt][nt] = (f32x4){0.f, 0.f, 0.f, 0.f};

  pn2s[t] = pn2[t];            // 512 threads, one each

  // b1 preload (keeps the loop free of stray VMEM)
  float b1v[7];
  #pragma unroll
  for (int nt = 0; nt < 7; ++nt) {
    const int c = wn * 112 + nt * 16 + lr;
    b1v[nt] = (c < H_SZ) ? b1[c] : 0.f;
  }

  // X staging roles: thread t -> (row sr, cols hg*4..hg*4+3); one float4/step
  const int sr = t >> 3;       // 0..63
  const int hg = t & 7;        // 0..7
  const int xslot = (((hg >> 1) ^ ((sr >> 1) & 3)) << 3) + (hg & 1) * 4;
  const float* xrow = X + (size_t)(row0 + sr) * F_SZ;

  // W glds roles (compile-time 4 per wave): lane l -> row c = ci*16+(l>>2),
  // phys granule l&3, pre-swizzled source granule (l&3)^((c>>1)&3)
  const int wrow_sub = l >> 2;
  const int wgr = l & 3;

  // ---- prologue: G(0)->Ws[0], G(1)->Ws[1]; X(0)->Xs[0]; xp <- X(1) ----
  float4 xp;
  {
    #pragma unroll
    for (int i = 0; i < 4; ++i) {
      const int ci = w + 8 * i;
      const int c = ci * 16 + wrow_sub;
      const int srcg = wgr ^ ((c >> 1) & 3);
      glds16(W1T + (size_t)c * 800 + srcg * 8, &wh.Ws[0][ci * 512]);
      glds16(W1T + (size_t)c * 800 + 32 + srcg * 8, &wh.Ws[1][ci * 512]);
    }
    const float4 x0 = *(const float4*)(xrow + hg * 4);
    short4v p;
    p[0] = f2bf(x0.x); p[1] = f2bf(x0.y); p[2] = f2bf(x0.z); p[3] = f2bf(x0.w);
    *(short4v*)&xz.Xs[0][sr][xslot] = p;
    xp = *(const float4*)(xrow + 32 + hg * 4);
  }
  __syncthreads();   // one-time full drain; steady-state invariant starts clean

  // ---- main loop: K-steps 0..20 (3-step unrolled), 21..22, tail 23..24 ----
  for (int kb = 0; kb < 21; kb += 3) {
    GSTEP(kb + 0, 0, 1, 2, 1, 1);
    GSTEP(kb + 1, 1, 2, 0, 1, 1);
    GSTEP(kb + 2, 2, 0, 1, 1, 1);
  }
  GSTEP(21, 0, 1, 2, 1, 1);
  GSTEP(22, 1, 2, 0, 1, 1);   // issues G(24)/X(24)
  GSTEP(23, 2, 0, 1, 0, 1);   // no issue; vmcnt(0) before X(24) write
  GSTEP(24, 0, 1, 2, 0, 0);   // compute only

  // ---- bias+relu -> hs (bf16, unions over Ws) ----
  #pragma unroll
  for (int nt = 0; nt < 7; ++nt) {
    const int c = wn * 112 + nt * 16 + lr;
    if (c < 416) {
      #pragma unroll
      for (int mt = 0; mt < 2; ++mt)
        #pragma unroll
        for (int rg = 0; rg < 4; ++rg) {
          const int row = wm * 32 + mt * 16 + 4 * lg + rg;
          const int cph = c ^ (((row >> 2) & 3) << 3);
          wh.hs[row * 448 + cph] = f2bf(fmaxf(acc[mt][nt][rg] + b1v[nt], 0.f));
        }
    }
  }
  __syncthreads();

  // ---- phase 2: z = h@W2 + b2 (wave: rowgrp w>>1, d-half w&1) ----
  {
    const int rL = (w >> 1) * 16 + lr;
    const int cD = (w & 1) * 16 + lr;
    const float b2v = (cD < D_SZ) ? b2[cD] : 0.f;
    f32x4 za = (f32x4){b2v, b2v, b2v, b2v};
    #pragma unroll
    for (int ks2 = 0; ks2 < 13; ++ks2) {
      const int u = 4 * ks2 + lg;
      const int up = u ^ ((rL >> 2) & 3);
      const short8v af = *(const short8v*)&wh.hs[rL * 448 + up * 8];
      const short8v bf = *(const short8v*)&W2T[cD * 416 + ks2 * 32 + lg * 8];
      za = __builtin_amdgcn_mfma_f32_16x16x32_bf16(af, bf, za, 0, 0, 0);
    }
    #pragma unroll
    for (int rg = 0; rg < 4; ++rg) {
      float s = za[rg] * za[rg];
      s += __shfl_xor(s, 1); s += __shfl_xor(s, 2);
      s += __shfl_xor(s, 4); s += __shfl_xor(s, 8);
      const int row = (w >> 1) * 16 + 4 * lg + rg;
      if (lr == 0) zn2p[w & 1][row] = s;
      xz.zs[row][cD] = f2bf(za[rg]);
    }
  }
  __syncthreads();

  // ---- phase 3 (waves 0..3): distances via MFMA, argmin, loss1, idx ----
  float lsum = 0.f;
  if (w < 4) {
    const int rowA = w * 16 + lr;
    const short8v zf = *(const short8v*)&xz.zs[rowA][lg * 8];
    float zn2r[4];
    #pragma unroll
    for (int rg = 0; rg < 4; ++rg) {
      const int row = w * 16 + 4 * lg + rg;
      zn2r[rg] = zn2p[0][row] + zn2p[1][row];
    }
    float bv[4] = {3.4e38f, 3.4e38f, 3.4e38f, 3.4e38f};
    int bi[4] = {0, 0, 0, 0};
    #pragma unroll 8
    for (int nt = 0; nt < 32; ++nt) {
      const int code = nt * 16 + lr;
      const short8v pf = *(const short8v*)&M2P[code * 32 + lg * 8];
      f32x4 dacc = (f32x4){zn2r[0], zn2r[1], zn2r[2], zn2r[3]};
      dacc = __builtin_amdgcn_mfma_f32_16x16x32_bf16(zf, pf, dacc, 0, 0, 0);
      const float pn = pn2s[code];
      #pragma unroll
      for (int rg = 0; rg < 4; ++rg) {
        const float dv = fmaxf(dacc[rg] + pn, 0.f);
        if (dv < bv[rg]) { bv[rg] = dv; bi[rg] = code; }  // ascending: first-min
      }
    }
    #pragma unroll
    for (int rg = 0; rg < 4; ++rg) {
      float v = bv[rg]; int ii = bi[rg];
      #pragma unroll
      for (int m = 1; m <= 8; m <<= 1) {
        const float ov = __shfl_xor(v, m);
        const int oi = __shfl_xor(ii, m);
        if (ov < v || (ov == v && oi < ii)) { v = ov; ii = oi; }
      }
      bv[rg] = v; bi[rg] = ii;
    }
    if (lr == 0) {
      lsum = bv[0] + bv[1] + bv[2] + bv[3];
      #pragma unroll
      for (int rg = 0; rg < 4; ++rg) idxs[w * 16 + 4 * lg + rg] = bi[rg];
    }
  }
  __syncthreads();

  // ---- fused loss_rec: 8 waves x 8 rows, Sum ||x - table[idx]||^2 ----
  float racc = 0.f;
  #pragma unroll 2
  for (int rr = 0; rr < 8; ++rr) {
    const int rge = w * 8 + rr;                  // 0..63
    const int kk = idxs[rge];
    const float4* xr4 = (const float4*)&X[(size_t)(row0 + rge) * F_SZ];
    const float4* tr4 = (const float4*)&table[(size_t)kk * F_SZ];
    #pragma unroll
    for (int s = 0; s < 3; ++s) {
      const int i = l + 64 * s;
      const float4 xv = xr4[i], tv = tr4[i];
      const float d0 = xv.x - tv.x, d1 = xv.y - tv.y, d2 = xv.z - tv.z, d3 = xv.w - tv.w;
      racc += d0 * d0 + d1 * d1 + d2 * d2 + d3 * d3;
    }
    if (l < 4) {
      const int i = 192 + l;
      const float4 xv = xr4[i], tv = tr4[i];
      const float d0 = xv.x - tv.x, d1 = xv.y - tv.y, d2 = xv.z - tv.z, d3 = xv.w - tv.w;
      racc += d0 * d0 + d1 * d1 + d2 * d2 + d3 * d3;
    }
  }

  // ---- block reduction ----
  #pragma unroll
  for (int m = 1; m <= 32; m <<= 1) {
    lsum += __shfl_xor(lsum, m);
    racc += __shfl_xor(racc, m);
  }
  if (l == 0) { red1[w] = lsum; redR[w] = racc; }
  __syncthreads();
  if (t == 0) {
    float s1 = 0.f, sr2 = 0.f;
    #pragma unroll
    for (int i = 0; i < 8; ++i) { s1 += red1[i]; sr2 += redR[i]; }
    partial1[blockIdx.x] = s1;
    partialR[blockIdx.x] = sr2;
  }
}

// ---------------------------------------------------------------------------
// Final: loss = (0.625*s1 + srec)/B   (loss_1 == loss_2 forward; 1.25*0.5)
// ---------------------------------------------------------------------------
__global__ __launch_bounds__(256) void final_kernel(
    const float* __restrict__ partial1, const float* __restrict__ partialR,
    float* __restrict__ out) {
  __shared__ float s1s[256], srs[256];
  const int t = threadIdx.x;
  float s1 = 0.f, sr = 0.f;
  for (int i = t; i < NBLK; i += 256) s1 += partial1[i];
  for (int i = t; i < NBLK; i += 256) sr += partialR[i];
  s1s[t] = s1; srs[t] = sr;
  __syncthreads();
  for (int off = 128; off > 0; off >>= 1) {
    if (t < off) { s1s[t] += s1s[t + off]; srs[t] += srs[t + off]; }
    __syncthreads();
  }
  if (t == 0) out[0] = (0.625f * s1s[0] + srs[0]) * (1.0f / (float)B_SZ);
}

extern "C" void kernel_launch(void* const* d_in, const int* in_sizes, int n_in,
                              void* d_out, int out_size, void* d_ws, size_t ws_size,
                              hipStream_t stream) {
  const float* X     = (const float*)d_in[0];
  const float* W1    = (const float*)d_in[1];
  const float* b1    = (const float*)d_in[2];
  const float* W2    = (const float*)d_in[3];
  const float* b2    = (const float*)d_in[4];
  const float* W3    = (const float*)d_in[5];
  const float* b3    = (const float*)d_in[6];
  const float* W4    = (const float*)d_in[7];
  const float* b4    = (const float*)d_in[8];
  const float* prior = (const float*)d_in[9];

  float* wsf   = (float*)d_ws;
  float* table = wsf;
  float* pn2   = wsf + WS_PN2;
  float* part1 = wsf + WS_P1;
  float* partR = wsf + WS_PR;
  short* W1T   = (short*)(wsf + WS_W1T);
  short* W2T   = (short*)(wsf + WS_W2T);
  short* M2P   = (short*)(wsf + WS_M2P);
  float* out   = (float*)d_out;

  precompute_kernel<<<dim3(K_SZ), dim3(256), 0, stream>>>(W3, b3, W4, b4, prior, table, pn2);
  w1t_kernel<<<dim3(13, 7), dim3(256), 0, stream>>>(W1, W1T);
  prep2_kernel<<<dim3(64), dim3(256), 0, stream>>>(W2, prior, W2T, M2P);
  encoder_kernel<<<dim3(NBLK), dim3(512), 0, stream>>>(
      X, W1T, b1, W2T, b2, M2P, pn2, table, part1, partR);
  final_kernel<<<dim3(1), dim3(256), 0, stream>>>(part1, partR, out);
}

// Round 12
// 359.418 us; speedup vs baseline: 1.3152x; 1.3152x over previous
//
#include <hip/hip_runtime.h>
#include <hip/hip_bf16.h>

// Problem sizes (fixed)
#define B_SZ 131072
#define F_SZ 784
#define H_SZ 392
#define D_SZ 28
#define K_SZ 512
#define BM   64
#define NBLK (B_SZ / BM)   // 2048

typedef __attribute__((ext_vector_type(8))) short short8v;
typedef __attribute__((ext_vector_type(4))) short short4v;
typedef __attribute__((ext_vector_type(4))) float f32x4;

__device__ inline short f2bf(float f) {
  __hip_bfloat16 h = __float2bfloat16(f);
  return __builtin_bit_cast(short, h);
}

__device__ inline void glds16(const short* src, short* dst) {
  __builtin_amdgcn_global_load_lds(
      (const __attribute__((address_space(1))) unsigned int*)src,
      (__attribute__((address_space(3))) unsigned int*)dst, 16, 0, 0);
}

// ws layout (float offsets)
#define WS_PN2   401408
#define WS_P1    532992
#define WS_PR    535040
#define WS_W1T   537088     // 448x800 bf16; rows 448..511 read harmless ws garbage
#define WS_W2T   716288
#define WS_M2P   722944

// ---------------------------------------------------------------------------
// Merged prep: [0,512) decoder table+pn2 | [512,603) W1T transpose | [603,667) W2T/M2P
// ---------------------------------------------------------------------------
__global__ __launch_bounds__(256) void prep_kernel(
    const float* __restrict__ W1, const float* __restrict__ W2,
    const float* __restrict__ W3, const float* __restrict__ b3,
    const float* __restrict__ W4, const float* __restrict__ b4,
    const float* __restrict__ prior,
    float* __restrict__ table, float* __restrict__ pn2,
    short* __restrict__ W1T, short* __restrict__ W2T, short* __restrict__ M2P) {
  __shared__ float smem[64 * 65];
  const int bx = blockIdx.x;
  const int t = threadIdx.x;
  if (bx < 512) {
    // decoder table row bx
    float* ps = smem;            // [28]
    float* h2s = smem + 32;      // [392]
    const int k = bx;
    if (t < D_SZ) ps[t] = prior[k * D_SZ + t];
    __syncthreads();
    for (int j = t; j < H_SZ; j += 256) {
      float acc = b3[j];
      #pragma unroll
      for (int d = 0; d < D_SZ; ++d) acc += ps[d] * W3[d * H_SZ + j];
      h2s[j] = fmaxf(acc, 0.f);
    }
    if (t == 0) {
      float s = 0.f;
      #pragma unroll
      for (int d = 0; d < D_SZ; ++d) s += ps[d] * ps[d];
      pn2[k] = s;
    }
    __syncthreads();
    for (int f = t; f < F_SZ; f += 256) {
      float acc = b4[f];
      for (int j = 0; j < H_SZ; ++j) acc += h2s[j] * W4[j * F_SZ + f];
      table[(size_t)k * F_SZ + f] = acc;
    }
  } else if (bx < 603) {
    // W1T[c][k] = bf16(W1[k][c]), [448][800] zero-padded
    float (*tile)[65] = (float(*)[65])smem;
    const int bx2 = bx - 512;
    const int k0 = (bx2 % 13) * 64;
    const int c0 = (bx2 / 13) * 64;
    for (int i = t; i < 4096; i += 256) {
      const int kk = i >> 6, cc = i & 63;
      const int k = k0 + kk, c = c0 + cc;
      tile[kk][cc] = (k < F_SZ && c < H_SZ) ? W1[(size_t)k * H_SZ + c] : 0.f;
    }
    __syncthreads();
    for (int i = t; i < 4096; i += 256) {
      const int cc = i >> 6, kk = i & 63;
      const int k = k0 + kk, c = c0 + cc;
      if (k < 800) W1T[(size_t)c * 800 + k] = f2bf(tile[kk][cc]);
    }
  } else {
    const int i = (bx - 603) * 256 + t;
    if (i < 32 * 416) {
      const int d = i / 416, j = i % 416;
      W2T[i] = f2bf((d < D_SZ && j < H_SZ) ? W2[(size_t)j * D_SZ + d] : 0.f);
    }
    if (i < K_SZ * 32) {
      const int c = i / 32, dd = i % 32;
      M2P[i] = f2bf((dd < D_SZ) ? -2.f * prior[(size_t)c * D_SZ + dd] : 0.f);
    }
  }
}

// ---------------------------------------------------------------------------
// Fused encoder v12 (consolidation): r9 GEMM loop (static glds counts, counted
// vmcnt(1), 2-way swizzles) + setprio around MFMA + r11 fused tails (absmax 0).
// BM=64, 512 thr / 8 waves (2M x 4N), acc[2][7]=56 regs.
// LDS 80,704 B <= 81,920 -> 2 blocks/CU (16 waves).
// ---------------------------------------------------------------------------
union WHS { short Ws[2][512 * 32]; short hs[64 * 448]; };  // 65,536 B

__global__ __launch_bounds__(512, 4) void encoder_kernel(
    const float* __restrict__ X, const short* __restrict__ W1T,
    const float* __restrict__ b1, const short* __restrict__ W2T,
    const float* __restrict__ b2, const short* __restrict__ M2P,
    const float* __restrict__ pn2, const float* __restrict__ table,
    float* __restrict__ partial1, float* __restrict__ partialR) {
  __shared__ WHS wh;                // 65,536 B
  __shared__ short Xs[2][BM][32];   //  8,192 B
  __shared__ short zs[BM][32];      //  4,096 B
  __shared__ float pn2s[K_SZ];      //  2,048 B
  __shared__ float zn2p[2][BM];     //    512 B
  __shared__ int   idxs[BM];        //    256 B
  __shared__ float red1[8], redR[8];

  const int t = threadIdx.x;
  const int w = t >> 6;        // wave 0..7
  const int l = t & 63;
  const int lr = l & 15;
  const int lg = l >> 4;       // 0..3
  const int wm = w >> 2;       // M-half: rows wm*32..
  const int wn = w & 3;        // N-quarter: cols wn*112..
  const int row0 = blockIdx.x * BM;

  f32x4 acc[2][7];
  #pragma unroll
  for (int mt = 0; mt < 2; ++mt)
    #pragma unroll
    for (int nt = 0; nt < 7; ++nt) acc[mt][nt] = (f32x4){0.f, 0.f, 0.f, 0.f};

  pn2s[t] = pn2[t];            // 512 threads, one each

  // X staging roles: thread t -> (row sr, cols hg*4..hg*4+3); one float4/step
  const int sr = t >> 3;       // 0..63
  const int hg = t & 7;        // 0..7
  const int xpg = (hg >> 1) ^ ((sr >> 1) & 3);
  short* const xdst_base = &Xs[0][sr][xpg * 8 + (hg & 1) * 4];
  const float* xrow = X + (size_t)(row0 + sr) * F_SZ;

  // W glds roles (compile-time 4/wave): lane l -> row c = ci*16+(l>>2),
  // phys granule l&3, pre-swizzled source granule (l&3)^((c>>1)&3)
  const int wrow_sub = l >> 2;
  const int wgr = l & 3;

  // ---- prologue: stage W(0) + X(0); xp <- tile 1; full drain once ----
  {
    #pragma unroll
    for (int i = 0; i < 4; ++i) {
      const int ci = w + 8 * i;
      const int c = ci * 16 + wrow_sub;
      const int srcg = wgr ^ ((c >> 1) & 3);
      glds16(W1T + (size_t)c * 800 + srcg * 8, &wh.Ws[0][ci * 512]);
    }
    const float4 x0 = *(const float4*)(xrow + hg * 4);
    short4v p;
    p[0] = f2bf(x0.x); p[1] = f2bf(x0.y); p[2] = f2bf(x0.z); p[3] = f2bf(x0.w);
    *(short4v*)xdst_base = p;
  }
  float4 xp = *(const float4*)(xrow + 32 + hg * 4);   // tile 1
  __syncthreads();

  // ---- main loop: 25 K-steps of 32 ----
  for (int ks = 0; ks < 25; ++ks) {
    const int cur = ks & 1, nxt = cur ^ 1;
    float4 xq = {0.f, 0.f, 0.f, 0.f};
    if (ks < 24) {
      const int k0n = (ks + 1) * 32;
      #pragma unroll
      for (int i = 0; i < 4; ++i) {                 // exactly 4 glds / wave
        const int ci = w + 8 * i;
        const int c = ci * 16 + wrow_sub;
        const int srcg = wgr ^ ((c >> 1) & 3);
        glds16(W1T + (size_t)c * 800 + k0n + srcg * 8, &wh.Ws[nxt][ci * 512]);
      }
      __builtin_amdgcn_sched_barrier(0);
      const int kt = (ks + 2 < 25) ? (ks + 2) : 24; // clamp: uniform count
      const int kg = kt * 32 + hg * 4;
      if (kg < F_SZ) xq = *(const float4*)(xrow + kg);
      __builtin_amdgcn_sched_barrier(0);
    }
    // MFMA cluster (LDS only), prioritized
    short8v afr[2];
    #pragma unroll
    for (int mt = 0; mt < 2; ++mt) {
      const int row = wm * 32 + mt * 16 + lr;
      const int pg = lg ^ ((row >> 1) & 3);
      afr[mt] = *(const short8v*)&Xs[cur][row][pg * 8];
    }
    __builtin_amdgcn_s_setprio(1);
    #pragma unroll
    for (int nt = 0; nt < 7; ++nt) {
      const int c = wn * 112 + nt * 16 + lr;
      const int pgb = lg ^ ((c >> 1) & 3);
      const short8v bfr = *(const short8v*)&wh.Ws[cur][c * 32 + pgb * 8];
      #pragma unroll
      for (int mt = 0; mt < 2; ++mt)
        acc[mt][nt] = __builtin_amdgcn_mfma_f32_16x16x32_bf16(afr[mt], bfr, acc[mt][nt], 0, 0, 0);
    }
    __builtin_amdgcn_s_setprio(0);
    if (ks < 24) {
      // write X(ks+1) from regs loaded LAST step (oldest outstanding)
      short4v p;
      p[0] = f2bf(xp.x); p[1] = f2bf(xp.y); p[2] = f2bf(xp.z); p[3] = f2bf(xp.w);
      *(short4v*)(xdst_base + (nxt ? BM * 32 : 0)) = p;
      xp = xq;
    }
    asm volatile("s_waitcnt vmcnt(1) lgkmcnt(0)" ::: "memory");
    __builtin_amdgcn_s_barrier();
  }
  asm volatile("" :: "v"(xp.x));   // keepalive: clamped dup load stays issued

  // ---- bias+relu -> hs (bf16, unions over Ws) ----
  float b1v[7];
  #pragma unroll
  for (int nt = 0; nt < 7; ++nt) {
    const int c = wn * 112 + nt * 16 + lr;
    b1v[nt] = (c < H_SZ) ? b1[c] : 0.f;
  }
  #pragma unroll
  for (int nt = 0; nt < 7; ++nt) {
    const int c = wn * 112 + nt * 16 + lr;
    if (c < 416) {
      #pragma unroll
      for (int mt = 0; mt < 2; ++mt)
        #pragma unroll
        for (int rg = 0; rg < 4; ++rg) {
          const int row = wm * 32 + mt * 16 + 4 * lg + rg;
          const int cph = c ^ (((row >> 2) & 3) << 3);
          wh.hs[row * 448 + cph] = f2bf(fmaxf(acc[mt][nt][rg] + b1v[nt], 0.f));
        }
    }
  }
  __syncthreads();

  // ---- phase 2: z = h@W2 + b2 (wave: rowgrp w>>1, d-half w&1) ----
  {
    const int rL = (w >> 1) * 16 + lr;
    const int cD = (w & 1) * 16 + lr;
    const float b2v = (cD < D_SZ) ? b2[cD] : 0.f;
    f32x4 za = (f32x4){b2v, b2v, b2v, b2v};
    #pragma unroll
    for (int ks2 = 0; ks2 < 13; ++ks2) {
      const int u = 4 * ks2 + lg;
      const int up = u ^ ((rL >> 2) & 3);
      const short8v af = *(const short8v*)&wh.hs[rL * 448 + up * 8];
      const short8v bf = *(const short8v*)&W2T[cD * 416 + ks2 * 32 + lg * 8];
      za = __builtin_amdgcn_mfma_f32_16x16x32_bf16(af, bf, za, 0, 0, 0);
    }
    #pragma unroll
    for (int rg = 0; rg < 4; ++rg) {
      float s = za[rg] * za[rg];
      s += __shfl_xor(s, 1); s += __shfl_xor(s, 2);
      s += __shfl_xor(s, 4); s += __shfl_xor(s, 8);
      const int row = (w >> 1) * 16 + 4 * lg + rg;
      if (lr == 0) zn2p[w & 1][row] = s;
      zs[row][cD] = f2bf(za[rg]);
    }
  }
  __syncthreads();

  // ---- phase 3 (waves 0..3): distances via MFMA, argmin, loss1, idx ----
  float lsum = 0.f;
  if (w < 4) {
    const int rowA = w * 16 + lr;
    const short8v zf = *(const short8v*)&zs[rowA][lg * 8];
    float zn2r[4];
    #pragma unroll
    for (int rg = 0; rg < 4; ++rg) {
      const int row = w * 16 + 4 * lg + rg;
      zn2r[rg] = zn2p[0][row] + zn2p[1][row];
    }
    float bv[4] = {3.4e38f, 3.4e38f, 3.4e38f, 3.4e38f};
    int bi[4] = {0, 0, 0, 0};
    #pragma unroll 8
    for (int nt = 0; nt < 32; ++nt) {
      const int code = nt * 16 + lr;
      const short8v pf = *(const short8v*)&M2P[code * 32 + lg * 8];
      f32x4 dacc = (f32x4){zn2r[0], zn2r[1], zn2r[2], zn2r[3]};
      dacc = __builtin_amdgcn_mfma_f32_16x16x32_bf16(zf, pf, dacc, 0, 0, 0);
      const float pn = pn2s[code];
      #pragma unroll
      for (int rg = 0; rg < 4; ++rg) {
        const float dv = fmaxf(dacc[rg] + pn, 0.f);
        if (dv < bv[rg]) { bv[rg] = dv; bi[rg] = code; }  // ascending: first-min
      }
    }
    #pragma unroll
    for (int rg = 0; rg < 4; ++rg) {
      float v = bv[rg]; int ii = bi[rg];
      #pragma unroll
      for (int m = 1; m <= 8; m <<= 1) {
        const float ov = __shfl_xor(v, m);
        const int oi = __shfl_xor(ii, m);
        if (ov < v || (ov == v && oi < ii)) { v = ov; ii = oi; }
      }
      bv[rg] = v; bi[rg] = ii;
    }
    if (lr == 0) {
      lsum = bv[0] + bv[1] + bv[2] + bv[3];
      #pragma unroll
      for (int rg = 0; rg < 4; ++rg) idxs[w * 16 + 4 * lg + rg] = bi[rg];
    }
  }
  __syncthreads();

  // ---- fused loss_rec: 8 waves x 8 rows, Sum ||x - table[idx]||^2 ----
  float racc = 0.f;
  #pragma unroll 2
  for (int rr = 0; rr < 8; ++rr) {
    const int rge = w * 8 + rr;                  // 0..63
    const int kk = idxs[rge];
    const float4* xr4 = (const float4*)&X[(size_t)(row0 + rge) * F_SZ];
    const float4* tr4 = (const float4*)&table[(size_t)kk * F_SZ];
    #pragma unroll
    for (int s = 0; s < 3; ++s) {
      const int i = l + 64 * s;
      const float4 xv = xr4[i], tv = tr4[i];
      const float d0 = xv.x - tv.x, d1 = xv.y - tv.y, d2 = xv.z - tv.z, d3 = xv.w - tv.w;
      racc += d0 * d0 + d1 * d1 + d2 * d2 + d3 * d3;
    }
    if (l < 4) {
      const int i = 192 + l;
      const float4 xv = xr4[i], tv = tr4[i];
      const float d0 = xv.x - tv.x, d1 = xv.y - tv.y, d2 = xv.z - tv.z, d3 = xv.w - tv.w;
      racc += d0 * d0 + d1 * d1 + d2 * d2 + d3 * d3;
    }
  }

  // ---- block reduction ----
  #pragma unroll
  for (int m = 1; m <= 32; m <<= 1) {
    lsum += __shfl_xor(lsum, m);
    racc += __shfl_xor(racc, m);
  }
  if (l == 0) { red1[w] = lsum; redR[w] = racc; }
  __syncthreads();
  if (t == 0) {
    float s1 = 0.f, sr2 = 0.f;
    #pragma unroll
    for (int i = 0; i < 8; ++i) { s1 += red1[i]; sr2 += redR[i]; }
    partial1[blockIdx.x] = s1;
    partialR[blockIdx.x] = sr2;
  }
}

// ---------------------------------------------------------------------------
// Final: loss = (0.625*s1 + srec)/B   (loss_1 == loss_2 forward; 1.25*0.5)
// ---------------------------------------------------------------------------
__global__ __launch_bounds__(256) void final_kernel(
    const float* __restrict__ partial1, const float* __restrict__ partialR,
    float* __restrict__ out) {
  __shared__ float s1s[256], srs[256];
  const int t = threadIdx.x;
  float s1 = 0.f, sr = 0.f;
  for (int i = t; i < NBLK; i += 256) s1 += partial1[i];
  for (int i = t; i < NBLK; i += 256) sr += partialR[i];
  s1s[t] = s1; srs[t] = sr;
  __syncthreads();
  for (int off = 128; off > 0; off >>= 1) {
    if (t < off) { s1s[t] += s1s[t + off]; srs[t] += srs[t + off]; }
    __syncthreads();
  }
  if (t == 0) out[0] = (0.625f * s1s[0] + srs[0]) * (1.0f / (float)B_SZ);
}

extern "C" void kernel_launch(void* const* d_in, const int* in_sizes, int n_in,
                              void* d_out, int out_size, void* d_ws, size_t ws_size,
                              hipStream_t stream) {
  const float* X     = (const float*)d_in[0];
  const float* W1    = (const float*)d_in[1];
  const float* b1    = (const float*)d_in[2];
  const float* W2    = (const float*)d_in[3];
  const float* b2    = (const float*)d_in[4];
  const float* W3    = (const float*)d_in[5];
  const float* b3    = (const float*)d_in[6];
  const float* W4    = (const float*)d_in[7];
  const float* b4    = (const float*)d_in[8];
  const float* prior = (const float*)d_in[9];

  float* wsf   = (float*)d_ws;
  float* table = wsf;
  float* pn2   = wsf + WS_PN2;
  float* part1 = wsf + WS_P1;
  float* partR = wsf + WS_PR;
  short* W1T   = (short*)(wsf + WS_W1T);
  short* W2T   = (short*)(wsf + WS_W2T);
  short* M2P   = (short*)(wsf + WS_M2P);
  float* out   = (float*)d_out;

  prep_kernel<<<dim3(667), dim3(256), 0, stream>>>(
      W1, W2, W3, b3, W4, b4, prior, table, pn2, W1T, W2T, M2P);
  encoder_kernel<<<dim3(NBLK), dim3(512), 0, stream>>>(
      X, W1T, b1, W2T, b2, M2P, pn2, table, part1, partR);
  final_kernel<<<dim3(1), dim3(256), 0, stream>>>(part1, partR, out);
}

// Round 13
// 354.231 us; speedup vs baseline: 1.3344x; 1.0146x over previous
//
#include <hip/hip_runtime.h>
#include <hip/hip_bf16.h>

// Problem sizes (fixed)
#define B_SZ 131072
#define F_SZ 784
#define H_SZ 392
#define D_SZ 28
#define K_SZ 512
#define BM   64
#define NBLK (B_SZ / BM)   // 2048

typedef __attribute__((ext_vector_type(8))) short short8v;
typedef __attribute__((ext_vector_type(4))) short short4v;
typedef __attribute__((ext_vector_type(4))) float f32x4;
typedef __attribute__((ext_vector_type(16))) float f32x16;

__device__ inline short f2bf(float f) {
  __hip_bfloat16 h = __float2bfloat16(f);
  return __builtin_bit_cast(short, h);
}

__device__ inline void glds16(const short* src, short* dst) {
  __builtin_amdgcn_global_load_lds(
      (const __attribute__((address_space(1))) unsigned int*)src,
      (__attribute__((address_space(3))) unsigned int*)dst, 16, 0, 0);
}

// ws layout (float offsets)
#define WS_PN2   401408
#define WS_P1    532992
#define WS_PR    535040
#define WS_W1T   537088     // 512x800 bf16 = 204800 floats (rows 448..511 zero)
#define WS_W2T   741888     // 32x416 bf16
#define WS_M2P   748544     // 512x32 bf16

// ---------------------------------------------------------------------------
// Merged prep: [0,512) table+pn2 | [512,616) W1T transpose 512x800 | [616,680) W2T/M2P
// ---------------------------------------------------------------------------
__global__ __launch_bounds__(256) void prep_kernel(
    const float* __restrict__ W1, const float* __restrict__ W2,
    const float* __restrict__ W3, const float* __restrict__ b3,
    const float* __restrict__ W4, const float* __restrict__ b4,
    const float* __restrict__ prior,
    float* __restrict__ table, float* __restrict__ pn2,
    short* __restrict__ W1T, short* __restrict__ W2T, short* __restrict__ M2P) {
  __shared__ float smem[64 * 65];
  const int bx = blockIdx.x;
  const int t = threadIdx.x;
  if (bx < 512) {
    float* ps = smem;            // [28]
    float* h2s = smem + 32;      // [392]
    const int k = bx;
    if (t < D_SZ) ps[t] = prior[k * D_SZ + t];
    __syncthreads();
    for (int j = t; j < H_SZ; j += 256) {
      float acc = b3[j];
      #pragma unroll
      for (int d = 0; d < D_SZ; ++d) acc += ps[d] * W3[d * H_SZ + j];
      h2s[j] = fmaxf(acc, 0.f);
    }
    if (t == 0) {
      float s = 0.f;
      #pragma unroll
      for (int d = 0; d < D_SZ; ++d) s += ps[d] * ps[d];
      pn2[k] = s;
    }
    __syncthreads();
    for (int f = t; f < F_SZ; f += 256) {
      float acc = b4[f];
      for (int j = 0; j < H_SZ; ++j) acc += h2s[j] * W4[j * F_SZ + f];
      table[(size_t)k * F_SZ + f] = acc;
    }
  } else if (bx < 616) {
    // W1T[c][k] = bf16(W1[k][c]), [512][800] zero-padded
    float (*tile)[65] = (float(*)[65])smem;
    const int bx2 = bx - 512;
    const int k0 = (bx2 % 13) * 64;
    const int c0 = (bx2 / 13) * 64;
    for (int i = t; i < 4096; i += 256) {
      const int kk = i >> 6, cc = i & 63;
      const int k = k0 + kk, c = c0 + cc;
      tile[kk][cc] = (k < F_SZ && c < H_SZ) ? W1[(size_t)k * H_SZ + c] : 0.f;
    }
    __syncthreads();
    for (int i = t; i < 4096; i += 256) {
      const int cc = i >> 6, kk = i & 63;
      const int k = k0 + kk, c = c0 + cc;
      if (k < 800) W1T[(size_t)c * 800 + k] = f2bf(tile[kk][cc]);
    }
  } else {
    const int i = (bx - 616) * 256 + t;
    if (i < 32 * 416) {
      const int d = i / 416, j = i % 416;
      W2T[i] = f2bf((d < D_SZ && j < H_SZ) ? W2[(size_t)j * D_SZ + d] : 0.f);
    }
    if (i < K_SZ * 32) {
      const int c = i / 32, dd = i % 32;
      M2P[i] = f2bf((dd < D_SZ) ? -2.f * prior[(size_t)c * D_SZ + dd] : 0.f);
    }
  }
}

// ---------------------------------------------------------------------------
// Fused encoder v13: 32x32x16 MFMA (2x FLOP/instruction -> 0.57x instruction
// count at N=512 pad). BM=64, 512 thr / 8 waves (2M x 4N), wave tile 32x128,
// acc = 4 x f32x16 = 64 regs. Per step: 2 A + 8 B ds_read_b128, 8 MFMA,
// 4 compile-time glds + 1 X float4. Plain __syncthreads() (best-measured
// discipline, r2/r5); no setprio / sched_barrier (r12 regressions).
// LDS 80,704 B -> 2 blocks/CU (16 waves). Tails r12-verbatim (absmax 0.0).
// C/D layout 32x32: col = lane&31, row = (reg&3) + 8*(reg>>2) + 4*(lane>>5).
// ---------------------------------------------------------------------------
union WHS { short Ws[2][512 * 32]; short hs[64 * 448]; };  // 65,536 B

__global__ __launch_bounds__(512, 4) void encoder_kernel(
    const float* __restrict__ X, const short* __restrict__ W1T,
    const float* __restrict__ b1, const short* __restrict__ W2T,
    const float* __restrict__ b2, const short* __restrict__ M2P,
    const float* __restrict__ pn2, const float* __restrict__ table,
    float* __restrict__ partial1, float* __restrict__ partialR) {
  __shared__ WHS wh;                // 65,536 B
  __shared__ short Xs[2][BM][32];   //  8,192 B
  __shared__ short zs[BM][32];      //  4,096 B
  __shared__ float pn2s[K_SZ];      //  2,048 B
  __shared__ float zn2p[2][BM];     //    512 B
  __shared__ int   idxs[BM];        //    256 B
  __shared__ float red1[8], redR[8];

  const int t = threadIdx.x;
  const int w = t >> 6;        // wave 0..7
  const int l = t & 63;
  const int lr = l & 15;
  const int lg = l >> 4;       // 0..3
  const int l31 = l & 31;
  const int hi = l >> 5;       // 0..1
  const int wm = w >> 2;       // M-half: rows wm*32..
  const int wn = w & 3;        // N-quarter: cols wn*128.. (of 512)
  const int row0 = blockIdx.x * BM;

  f32x16 acc[4];
  #pragma unroll
  for (int nt = 0; nt < 4; ++nt)
    #pragma unroll
    for (int q = 0; q < 16; ++q) acc[nt][q] = 0.f;

  pn2s[t] = pn2[t];            // 512 threads, one each

  // X staging roles: thread t -> (row sr, cols hg*4..hg*4+3); one float4/step
  const int sr = t >> 3;       // 0..63
  const int hg = t & 7;        // 0..7
  const int xpg = (hg >> 1) ^ ((sr >> 1) & 3);
  short* const xdst_base = &Xs[0][sr][xpg * 8 + (hg & 1) * 4];
  const float* xrow = X + (size_t)(row0 + sr) * F_SZ;

  // W glds roles (compile-time 4/wave over 32 chunks of 16 rows):
  // lane l -> row c = ci*16+(l>>2), phys granule l&3,
  // pre-swizzled source granule (l&3)^((c>>1)&3)
  const int wrow_sub = l >> 2;
  const int wgr = l & 3;

  // ---- prologue: stage W(0) + X(0); xp <- tile 1; drain once ----
  {
    #pragma unroll
    for (int i = 0; i < 4; ++i) {
      const int ci = w + 8 * i;
      const int c = ci * 16 + wrow_sub;
      const int srcg = wgr ^ ((c >> 1) & 3);
      glds16(W1T + (size_t)c * 800 + srcg * 8, &wh.Ws[0][ci * 512]);
    }
    const float4 x0 = *(const float4*)(xrow + hg * 4);
    short4v p;
    p[0] = f2bf(x0.x); p[1] = f2bf(x0.y); p[2] = f2bf(x0.z); p[3] = f2bf(x0.w);
    *(short4v*)xdst_base = p;
  }
  float4 xp = *(const float4*)(xrow + 32 + hg * 4);   // tile 1
  __syncthreads();

  // ---- main loop: 25 K-steps of 32 ----
  const int rowA = wm * 32 + l31;
  for (int ks = 0; ks < 25; ++ks) {
    const int cur = ks & 1, nxt = cur ^ 1;
    float4 xq = {0.f, 0.f, 0.f, 0.f};
    if (ks < 24) {
      const int k0n = (ks + 1) * 32;
      #pragma unroll
      for (int i = 0; i < 4; ++i) {                 // exactly 4 glds / wave
        const int ci = w + 8 * i;
        const int c = ci * 16 + wrow_sub;
        const int srcg = wgr ^ ((c >> 1) & 3);
        glds16(W1T + (size_t)c * 800 + k0n + srcg * 8, &wh.Ws[nxt][ci * 512]);
      }
      const int kt = (ks + 2 < 25) ? (ks + 2) : 24; // clamp: uniform count
      const int kg = kt * 32 + hg * 4;
      if (kg < F_SZ) xq = *(const float4*)(xrow + kg);
    }
    // MFMA cluster: 2 k-subs x (1 A-read + 4 x (B-read + 32x32x16 MFMA))
    #pragma unroll
    for (int ksub = 0; ksub < 2; ++ksub) {
      const int lgA = ksub * 2 + hi;               // logical 8-short granule
      const int pgA = lgA ^ ((rowA >> 1) & 3);
      const short8v afr = *(const short8v*)&Xs[cur][rowA][pgA * 8];
      #pragma unroll
      for (int nt = 0; nt < 4; ++nt) {
        const int c = wn * 128 + nt * 32 + l31;
        const int pgb = lgA ^ ((c >> 1) & 3);
        const short8v bfr = *(const short8v*)&wh.Ws[cur][c * 32 + pgb * 8];
        acc[nt] = __builtin_amdgcn_mfma_f32_32x32x16_bf16(afr, bfr, acc[nt], 0, 0, 0);
      }
    }
    if (ks < 24) {
      // write X(ks+1) from regs loaded LAST step
      short4v p;
      p[0] = f2bf(xp.x); p[1] = f2bf(xp.y); p[2] = f2bf(xp.z); p[3] = f2bf(xp.w);
      *(short4v*)(xdst_base + (nxt ? BM * 32 : 0)) = p;
      xp = xq;
    }
    __syncthreads();
  }
  asm volatile("" :: "v"(xp.x));   // keepalive: clamped dup load

  // ---- bias+relu -> hs (bf16, unions over Ws; 32x32 C/D layout) ----
  float b1v[4];
  #pragma unroll
  for (int nt = 0; nt < 4; ++nt) {
    const int c = wn * 128 + nt * 32 + l31;
    b1v[nt] = (c < H_SZ) ? b1[c] : 0.f;
  }
  #pragma unroll
  for (int nt = 0; nt < 4; ++nt) {
    const int c = wn * 128 + nt * 32 + l31;
    if (c < 416) {
      #pragma unroll
      for (int q = 0; q < 16; ++q) {
        const int row = wm * 32 + (q & 3) + 8 * (q >> 2) + 4 * hi;
        const int cph = c ^ (((row >> 2) & 3) << 3);
        wh.hs[row * 448 + cph] = f2bf(fmaxf(acc[nt][q] + b1v[nt], 0.f));
      }
    }
  }
  __syncthreads();

  // ---- phase 2: z = h@W2 + b2 (wave: rowgrp w>>1, d-half w&1) ----
  {
    const int rL = (w >> 1) * 16 + lr;
    const int cD = (w & 1) * 16 + lr;
    const float b2v = (cD < D_SZ) ? b2[cD] : 0.f;
    f32x4 za = (f32x4){b2v, b2v, b2v, b2v};
    #pragma unroll
    for (int ks2 = 0; ks2 < 13; ++ks2) {
      const int u = 4 * ks2 + lg;
      const int up = u ^ ((rL >> 2) & 3);
      const short8v af = *(const short8v*)&wh.hs[rL * 448 + up * 8];
      const short8v bf = *(const short8v*)&W2T[cD * 416 + ks2 * 32 + lg * 8];
      za = __builtin_amdgcn_mfma_f32_16x16x32_bf16(af, bf, za, 0, 0, 0);
    }
    #pragma unroll
    for (int rg = 0; rg < 4; ++rg) {
      float s = za[rg] * za[rg];
      s += __shfl_xor(s, 1); s += __shfl_xor(s, 2);
      s += __shfl_xor(s, 4); s += __shfl_xor(s, 8);
      const int row = (w >> 1) * 16 + 4 * lg + rg;
      if (lr == 0) zn2p[w & 1][row] = s;
      zs[row][cD] = f2bf(za[rg]);
    }
  }
  __syncthreads();

  // ---- phase 3 (waves 0..3): distances via MFMA, argmin, loss1, idx ----
  float lsum = 0.f;
  if (w < 4) {
    const int rowz = w * 16 + lr;
    const short8v zf = *(const short8v*)&zs[rowz][lg * 8];
    float zn2r[4];
    #pragma unroll
    for (int rg = 0; rg < 4; ++rg) {
      const int row = w * 16 + 4 * lg + rg;
      zn2r[rg] = zn2p[0][row] + zn2p[1][row];
    }
    float bv[4] = {3.4e38f, 3.4e38f, 3.4e38f, 3.4e38f};
    int bi[4] = {0, 0, 0, 0};
    #pragma unroll 8
    for (int nt = 0; nt < 32; ++nt) {
      const int code = nt * 16 + lr;
      const short8v pf = *(const short8v*)&M2P[code * 32 + lg * 8];
      f32x4 dacc = (f32x4){zn2r[0], zn2r[1], zn2r[2], zn2r[3]};
      dacc = __builtin_amdgcn_mfma_f32_16x16x32_bf16(zf, pf, dacc, 0, 0, 0);
      const float pn = pn2s[code];
      #pragma unroll
      for (int rg = 0; rg < 4; ++rg) {
        const float dv = fmaxf(dacc[rg] + pn, 0.f);
        if (dv < bv[rg]) { bv[rg] = dv; bi[rg] = code; }  // ascending: first-min
      }
    }
    #pragma unroll
    for (int rg = 0; rg < 4; ++rg) {
      float v = bv[rg]; int ii = bi[rg];
      #pragma unroll
      for (int m = 1; m <= 8; m <<= 1) {
        const float ov = __shfl_xor(v, m);
        const int oi = __shfl_xor(ii, m);
        if (ov < v || (ov == v && oi < ii)) { v = ov; ii = oi; }
      }
      bv[rg] = v; bi[rg] = ii;
    }
    if (lr == 0) {
      lsum = bv[0] + bv[1] + bv[2] + bv[3];
      #pragma unroll
      for (int rg = 0; rg < 4; ++rg) idxs[w * 16 + 4 * lg + rg] = bi[rg];
    }
  }
  __syncthreads();

  // ---- fused loss_rec: 8 waves x 8 rows, Sum ||x - table[idx]||^2 ----
  float racc = 0.f;
  #pragma unroll 2
  for (int rr = 0; rr < 8; ++rr) {
    const int rge = w * 8 + rr;                  // 0..63
    const int kk = idxs[rge];
    const float4* xr4 = (const float4*)&X[(size_t)(row0 + rge) * F_SZ];
    const float4* tr4 = (const float4*)&table[(size_t)kk * F_SZ];
    #pragma unroll
    for (int s = 0; s < 3; ++s) {
      const int i = l + 64 * s;
      const float4 xv = xr4[i], tv = tr4[i];
      const float d0 = xv.x - tv.x, d1 = xv.y - tv.y, d2 = xv.z - tv.z, d3 = xv.w - tv.w;
      racc += d0 * d0 + d1 * d1 + d2 * d2 + d3 * d3;
    }
    if (l < 4) {
      const int i = 192 + l;
      const float4 xv = xr4[i], tv = tr4[i];
      const float d0 = xv.x - tv.x, d1 = xv.y - tv.y, d2 = xv.z - tv.z, d3 = xv.w - tv.w;
      racc += d0 * d0 + d1 * d1 + d2 * d2 + d3 * d3;
    }
  }

  // ---- block reduction ----
  #pragma unroll
  for (int m = 1; m <= 32; m <<= 1) {
    lsum += __shfl_xor(lsum, m);
    racc += __shfl_xor(racc, m);
  }
  if (l == 0) { red1[w] = lsum; redR[w] = racc; }
  __syncthreads();
  if (t == 0) {
    float s1 = 0.f, sr2 = 0.f;
    #pragma unroll
    for (int i = 0; i < 8; ++i) { s1 += red1[i]; sr2 += redR[i]; }
    partial1[blockIdx.x] = s1;
    partialR[blockIdx.x] = sr2;
  }
}

// ---------------------------------------------------------------------------
// Final: loss = (0.625*s1 + srec)/B   (loss_1 == loss_2 forward; 1.25*0.5)
// ---------------------------------------------------------------------------
__global__ __launch_bounds__(256) void final_kernel(
    const float* __restrict__ partial1, const float* __restrict__ partialR,
    float* __restrict__ out) {
  __shared__ float s1s[256], srs[256];
  const int t = threadIdx.x;
  float s1 = 0.f, sr = 0.f;
  for (int i = t; i < NBLK; i += 256) s1 += partial1[i];
  for (int i = t; i < NBLK; i += 256) sr += partialR[i];
  s1s[t] = s1; srs[t] = sr;
  __syncthreads();
  for (int off = 128; off > 0; off >>= 1) {
    if (t < off) { s1s[t] += s1s[t + off]; srs[t] += srs[t + off]; }
    __syncthreads();
  }
  if (t == 0) out[0] = (0.625f * s1s[0] + srs[0]) * (1.0f / (float)B_SZ);
}

extern "C" void kernel_launch(void* const* d_in, const int* in_sizes, int n_in,
                              void* d_out, int out_size, void* d_ws, size_t ws_size,
                              hipStream_t stream) {
  const float* X     = (const float*)d_in[0];
  const float* W1    = (const float*)d_in[1];
  const float* b1    = (const float*)d_in[2];
  const float* W2    = (const float*)d_in[3];
  const float* b2    = (const float*)d_in[4];
  const float* W3    = (const float*)d_in[5];
  const float* b3    = (const float*)d_in[6];
  const float* W4    = (const float*)d_in[7];
  const float* b4    = (const float*)d_in[8];
  const float* prior = (const float*)d_in[9];

  float* wsf   = (float*)d_ws;
  float* table = wsf;
  float* pn2   = wsf + WS_PN2;
  float* part1 = wsf + WS_P1;
  float* partR = wsf + WS_PR;
  short* W1T   = (short*)(wsf + WS_W1T);
  short* W2T   = (short*)(wsf + WS_W2T);
  short* M2P   = (short*)(wsf + WS_M2P);
  float* out   = (float*)d_out;

  prep_kernel<<<dim3(680), dim3(256), 0, stream>>>(
      W1, W2, W3, b3, W4, b4, prior, table, pn2, W1T, W2T, M2P);
  encoder_kernel<<<dim3(NBLK), dim3(512), 0, stream>>>(
      X, W1T, b1, W2T, b2, M2P, pn2, table, part1, partR);
  final_kernel<<<dim3(1), dim3(256), 0, stream>>>(part1, partR, out);
}